// Round 1
// baseline (2658.960 us; speedup 1.0000x reference)
//
#include <hip/hip_runtime.h>
#include <stdint.h>

// Problem constants (fixed by the reference)
#define B_ 4
#define T_ 512
#define L_ 15
#define D_ 2048
#define H_ 1024
#define TL_ (T_*L_)            // 7680
#define M_ (B_*TL_)            // 30720
#define K_SPANS 205
#define NSORT 8192

// d_out float offsets (outputs concatenated flat in return order)
#define OFF_PRUNE 0                                   // [B,T,L,1]  30720
#define OFF_TOP   (OFF_PRUNE + M_)                    // [B,K]      820
#define OFF_FVECS (OFF_TOP + B_*K_SPANS)              // [B,K,D]    1679360
#define OFF_FSC   (OFF_FVECS + B_*K_SPANS*D_)         // [B,K,1]    820
#define OFF_FBEG  (OFF_FSC + B_*K_SPANS)              // [B,K,1]    820
#define OFF_FEND  (OFF_FBEG + B_*K_SPANS)             // [B,K,1]    820
#define OFF_SL    (OFF_FEND + B_*K_SPANS)             // [B]        4
#define OFF_SQ    (OFF_SL + B_)                       // [B,K,K]    168100
#define OFF_TRI   (OFF_SQ + B_*K_SPANS*K_SPANS)       // [B,K,K]    168100

// ---------------------------------------------------------------------------
// GEMM1: C = relu(A @ W + bias), A [M,K] rm, W [K,N] rm, C [M,N] rm.
// 128x128 tile, BK=16, 256 threads, 8x8 micro-tile per thread.
// ---------------------------------------------------------------------------
__global__ __launch_bounds__(256) void gemm1_relu(
    const float* __restrict__ A, const float* __restrict__ W,
    const float* __restrict__ bias, float* __restrict__ C,
    int M, int N, int K)
{
    __shared__ float As[16][132];   // +4 pad breaks 4-way bank conflict on transposed store
    __shared__ float Bs[16][128];

    const int tid  = threadIdx.x;
    const int m0   = blockIdx.y * 128;
    const int n0   = blockIdx.x * 128;
    const int arow = tid >> 2;            // 0..63
    const int acol = (tid & 3) << 2;      // 0,4,8,12
    const int brow = tid >> 5;            // 0..7
    const int bcol = (tid & 31) << 2;     // 0..124
    const int tx   = tid & 15;
    const int ty   = tid >> 4;
    const int tx8  = tx * 8;
    const int ty8  = ty * 8;

    const float* Aptr0 = A + (size_t)(m0 + arow) * K + acol;
    const float* Aptr1 = Aptr0 + (size_t)64 * K;
    const float* Wptr0 = W + (size_t)brow * N + n0 + bcol;
    const float* Wptr1 = Wptr0 + (size_t)8 * N;

    float acc[8][8];
    #pragma unroll
    for (int i = 0; i < 8; ++i)
        #pragma unroll
        for (int j = 0; j < 8; ++j) acc[i][j] = 0.f;

    const int KT = K >> 4;
    for (int kt = 0; kt < KT; ++kt) {
        const int k0 = kt << 4;
        float4 a0 = *(const float4*)(Aptr0 + k0);
        float4 a1 = *(const float4*)(Aptr1 + k0);
        float4 w0 = *(const float4*)(Wptr0 + (size_t)k0 * N);
        float4 w1 = *(const float4*)(Wptr1 + (size_t)k0 * N);
        __syncthreads();
        As[acol + 0][arow] = a0.x; As[acol + 1][arow] = a0.y;
        As[acol + 2][arow] = a0.z; As[acol + 3][arow] = a0.w;
        As[acol + 0][arow + 64] = a1.x; As[acol + 1][arow + 64] = a1.y;
        As[acol + 2][arow + 64] = a1.z; As[acol + 3][arow + 64] = a1.w;
        *(float4*)&Bs[brow][bcol]     = w0;
        *(float4*)&Bs[brow + 8][bcol] = w1;
        __syncthreads();
        #pragma unroll
        for (int k = 0; k < 16; ++k) {
            float av[8], bv[8];
            *(float4*)&av[0] = *(const float4*)&As[k][ty8];
            *(float4*)&av[4] = *(const float4*)&As[k][ty8 + 4];
            *(float4*)&bv[0] = *(const float4*)&Bs[k][tx8];
            *(float4*)&bv[4] = *(const float4*)&Bs[k][tx8 + 4];
            #pragma unroll
            for (int i = 0; i < 8; ++i)
                #pragma unroll
                for (int j = 0; j < 8; ++j)
                    acc[i][j] = fmaf(av[i], bv[j], acc[i][j]);
        }
    }

    const float4 bias0 = *(const float4*)(bias + n0 + tx8);
    const float4 bias1 = *(const float4*)(bias + n0 + tx8 + 4);
    #pragma unroll
    for (int i = 0; i < 8; ++i) {
        float* Crow = C + (size_t)(m0 + ty8 + i) * N + n0 + tx8;
        float4 o0, o1;
        o0.x = fmaxf(acc[i][0] + bias0.x, 0.f);
        o0.y = fmaxf(acc[i][1] + bias0.y, 0.f);
        o0.z = fmaxf(acc[i][2] + bias0.z, 0.f);
        o0.w = fmaxf(acc[i][3] + bias0.w, 0.f);
        o1.x = fmaxf(acc[i][4] + bias1.x, 0.f);
        o1.y = fmaxf(acc[i][5] + bias1.y, 0.f);
        o1.z = fmaxf(acc[i][6] + bias1.z, 0.f);
        o1.w = fmaxf(acc[i][7] + bias1.w, 0.f);
        *(float4*)Crow       = o0;
        *(float4*)(Crow + 4) = o1;
    }
}

// ---------------------------------------------------------------------------
// GEMM2 fused with W3 matvec: partial[cb][m] = sum_{n in col-block cb}
//   relu(h1[m,:]@W2[:,n] + b2[n]) * W3[n].   h2 never materialized.
// Deterministic (ordered LDS tree reduce, no atomics) so scores are
// bit-identical across launches (top-k selection stability under replay).
// ---------------------------------------------------------------------------
__global__ __launch_bounds__(256) void gemm2_score(
    const float* __restrict__ A, const float* __restrict__ W,
    const float* __restrict__ b2, const float* __restrict__ W3,
    float* __restrict__ partial, int M, int N, int K)
{
    __shared__ float As[16][132];
    __shared__ float Bs[16][128];
    __shared__ float sred[16][128];

    const int tid  = threadIdx.x;
    const int m0   = blockIdx.y * 128;
    const int n0   = blockIdx.x * 128;
    const int arow = tid >> 2;
    const int acol = (tid & 3) << 2;
    const int brow = tid >> 5;
    const int bcol = (tid & 31) << 2;
    const int tx   = tid & 15;
    const int ty   = tid >> 4;
    const int tx8  = tx * 8;
    const int ty8  = ty * 8;

    const float* Aptr0 = A + (size_t)(m0 + arow) * K + acol;
    const float* Aptr1 = Aptr0 + (size_t)64 * K;
    const float* Wptr0 = W + (size_t)brow * N + n0 + bcol;
    const float* Wptr1 = Wptr0 + (size_t)8 * N;

    float acc[8][8];
    #pragma unroll
    for (int i = 0; i < 8; ++i)
        #pragma unroll
        for (int j = 0; j < 8; ++j) acc[i][j] = 0.f;

    const int KT = K >> 4;
    for (int kt = 0; kt < KT; ++kt) {
        const int k0 = kt << 4;
        float4 a0 = *(const float4*)(Aptr0 + k0);
        float4 a1 = *(const float4*)(Aptr1 + k0);
        float4 w0 = *(const float4*)(Wptr0 + (size_t)k0 * N);
        float4 w1 = *(const float4*)(Wptr1 + (size_t)k0 * N);
        __syncthreads();
        As[acol + 0][arow] = a0.x; As[acol + 1][arow] = a0.y;
        As[acol + 2][arow] = a0.z; As[acol + 3][arow] = a0.w;
        As[acol + 0][arow + 64] = a1.x; As[acol + 1][arow + 64] = a1.y;
        As[acol + 2][arow + 64] = a1.z; As[acol + 3][arow + 64] = a1.w;
        *(float4*)&Bs[brow][bcol]     = w0;
        *(float4*)&Bs[brow + 8][bcol] = w1;
        __syncthreads();
        #pragma unroll
        for (int k = 0; k < 16; ++k) {
            float av[8], bv[8];
            *(float4*)&av[0] = *(const float4*)&As[k][ty8];
            *(float4*)&av[4] = *(const float4*)&As[k][ty8 + 4];
            *(float4*)&bv[0] = *(const float4*)&Bs[k][tx8];
            *(float4*)&bv[4] = *(const float4*)&Bs[k][tx8 + 4];
            #pragma unroll
            for (int i = 0; i < 8; ++i)
                #pragma unroll
                for (int j = 0; j < 8; ++j)
                    acc[i][j] = fmaf(av[i], bv[j], acc[i][j]);
        }
    }

    float w3v[8], b2v[8];
    *(float4*)&w3v[0] = *(const float4*)(W3 + n0 + tx8);
    *(float4*)&w3v[4] = *(const float4*)(W3 + n0 + tx8 + 4);
    *(float4*)&b2v[0] = *(const float4*)(b2 + n0 + tx8);
    *(float4*)&b2v[4] = *(const float4*)(b2 + n0 + tx8 + 4);

    #pragma unroll
    for (int i = 0; i < 8; ++i) {
        float rs = 0.f;
        #pragma unroll
        for (int j = 0; j < 8; ++j)
            rs += fmaxf(acc[i][j] + b2v[j], 0.f) * w3v[j];
        sred[tx][ty8 + i] = rs;
    }
    __syncthreads();
    if (tid < 128) {
        float s = 0.f;
        #pragma unroll
        for (int t = 0; t < 16; ++t) s += sred[t][tid];
        partial[(size_t)blockIdx.x * M + (m0 + tid)] = s;
    }
}

// ---------------------------------------------------------------------------
// Top-K per batch: bitonic sort of (ordered_score, ~idx) u64 keys in LDS,
// cutoff at rank K, ballot-scan compaction in ascending-index order
// (produces sorted top_idx for free). Also writes prune_scores, f_scores,
// f_begin, f_end, span_lengths.
// ---------------------------------------------------------------------------
__device__ __forceinline__ uint64_t score_key(float s, int idx) {
    unsigned u = __float_as_uint(s);
    u = (u & 0x80000000u) ? ~u : (u | 0x80000000u);     // monotonic float->uint
    return ((uint64_t)u << 32) | (uint64_t)(0xFFFFFFFFu - (unsigned)idx);
}

__device__ __forceinline__ float compute_score(
    const float* __restrict__ partial, const float* __restrict__ mask,
    float b3v, int b, int i)
{
    const int m = b * TL_ + i;
    float s = b3v;
    #pragma unroll
    for (int cb = 0; cb < 8; ++cb) s += partial[(size_t)cb * M_ + m];
    s -= (1.0f - mask[m]) * 10000.0f;
    return s;
}

__global__ __launch_bounds__(1024) void topk_kernel(
    const float* __restrict__ partial, const float* __restrict__ span_mask,
    const int* __restrict__ span_begin, const int* __restrict__ span_end,
    const int* __restrict__ seq_len, const float* __restrict__ b3,
    float* __restrict__ out, int* __restrict__ topk_ws)
{
    __shared__ uint64_t keys[NSORT];          // 64 KB exactly
    const int tid = threadIdx.x;
    const int b   = blockIdx.x;
    const float b3v = b3[0];

    for (int i = tid; i < NSORT; i += 1024) {
        if (i < TL_) {
            float s = compute_score(partial, span_mask, b3v, b, i);
            out[OFF_PRUNE + b * TL_ + i] = s;
            keys[i] = score_key(s, i);
        } else {
            keys[i] = 0ull;                   // sorts below any real score
        }
    }
    __syncthreads();

    // bitonic sort, descending
    for (unsigned kk = 2; kk <= NSORT; kk <<= 1) {
        for (unsigned j = kk >> 1; j > 0; j >>= 1) {
            for (unsigned i = (unsigned)tid; i < NSORT; i += 1024) {
                unsigned ixj = i ^ j;
                if (ixj > i) {
                    uint64_t x = keys[i], y = keys[ixj];
                    bool desc = ((i & kk) == 0);
                    if (desc ? (x < y) : (x > y)) { keys[i] = y; keys[ixj] = x; }
                }
            }
            __syncthreads();
        }
    }

    const uint64_t cutoff = keys[K_SPANS - 1];
    __syncthreads();

    // compaction in ascending index order => top_idx comes out sorted
    unsigned* sScan = (unsigned*)keys;        // reuse LDS (cutoff already in reg)
    unsigned base = 0;
    const unsigned lane = tid & 63;
    const unsigned wv   = tid >> 6;
    for (int c = 0; c < TL_; c += 1024) {
        const int i = c + tid;
        bool flag = false; float s = 0.f;
        if (i < TL_) {
            s = compute_score(partial, span_mask, b3v, b, i);  // bit-identical to pass 1
            flag = (score_key(s, i) >= cutoff);
        }
        uint64_t bal = __ballot(flag);
        unsigned pre = (unsigned)__popcll(bal & ((1ull << lane) - 1ull));
        if (lane == 0) sScan[wv] = (unsigned)__popcll(bal);
        __syncthreads();
        unsigned woff = 0, tot = 0;
        for (int w = 0; w < 16; ++w) {
            unsigned v = sScan[w];
            if (w < (int)wv) woff += v;
            tot += v;
        }
        if (flag) {
            const int g = b * K_SPANS + (int)(base + woff + pre);
            topk_ws[g]       = i;
            out[OFF_TOP + g] = (float)i;
            out[OFF_FSC + g] = s;
            out[OFF_FBEG + g] = (float)span_begin[b * TL_ + i];
            out[OFF_FEND + g] = (float)span_end[b * TL_ + i];
        }
        base += tot;
        __syncthreads();
    }

    if (tid == 0)
        out[OFF_SL + b] = ceilf(0.4f * (float)seq_len[b]);  // fp32 mul matches jax
}

// ---------------------------------------------------------------------------
__global__ void gather_vecs(const float* __restrict__ span_vecs,
                            const int* __restrict__ topk_ws,
                            float* __restrict__ out)
{
    const int bk  = blockIdx.x;               // 0 .. B*K-1
    const int b   = bk / K_SPANS;
    const int row = topk_ws[bk];
    const float4* src = (const float4*)(span_vecs + ((size_t)b * TL_ + row) * D_);
    float4* dst = (float4*)(out + OFF_FVECS + (size_t)bk * D_);
    for (int j = threadIdx.x; j < D_ / 4; j += blockDim.x) dst[j] = src[j];
}

__global__ void masks_kernel(const int* __restrict__ seq_len,
                             float* __restrict__ out)
{
    const int idx = blockIdx.x * blockDim.x + threadIdx.x;
    if (idx >= B_ * K_SPANS * K_SPANS) return;
    const int b = idx / (K_SPANS * K_SPANS);
    const int r = idx - b * K_SPANS * K_SPANS;
    const int i = r / K_SPANS;
    const int j = r - i * K_SPANS;
    const int sl = (int)ceilf(0.4f * (float)seq_len[b]);
    const float v = (i < sl && j < sl) ? 1.0f : 0.0f;
    out[OFF_SQ + idx]  = v;
    out[OFF_TRI + idx] = (j <= i) ? v : 0.0f;
}

// ---------------------------------------------------------------------------
extern "C" void kernel_launch(void* const* d_in, const int* in_sizes, int n_in,
                              void* d_out, int out_size, void* d_ws, size_t ws_size,
                              hipStream_t stream)
{
    const float* span_vecs  = (const float*)d_in[0];
    const float* span_mask  = (const float*)d_in[1];
    const int*   span_begin = (const int*)  d_in[2];
    const int*   span_end   = (const int*)  d_in[3];
    const int*   seq_len    = (const int*)  d_in[4];
    const float* W1 = (const float*)d_in[5];
    const float* b1 = (const float*)d_in[6];
    const float* W2 = (const float*)d_in[7];
    const float* b2 = (const float*)d_in[8];
    const float* W3 = (const float*)d_in[9];
    const float* b3 = (const float*)d_in[10];
    float* out = (float*)d_out;

    // workspace layout: h1 [M,H] fp32 (126 MB) | partial [8,M] | topk idx [B,K]
    float* h1      = (float*)d_ws;
    float* partial = h1 + (size_t)M_ * H_;
    int*   topk_ws = (int*)(partial + (size_t)8 * M_);

    gemm1_relu<<<dim3(H_ / 128, M_ / 128), 256, 0, stream>>>(
        span_vecs, W1, b1, h1, M_, H_, D_);
    gemm2_score<<<dim3(H_ / 128, M_ / 128), 256, 0, stream>>>(
        h1, W2, b2, W3, partial, M_, H_, H_);
    topk_kernel<<<B_, 1024, 0, stream>>>(
        partial, span_mask, span_begin, span_end, seq_len, b3, out, topk_ws);
    gather_vecs<<<B_ * K_SPANS, 256, 0, stream>>>(span_vecs, topk_ws, out);
    masks_kernel<<<(B_ * K_SPANS * K_SPANS + 255) / 256, 256, 0, stream>>>(
        seq_len, out);
}

// Round 2
// 1700.122 us; speedup vs baseline: 1.5640x; 1.5640x over previous
//
#include <hip/hip_runtime.h>
#include <stdint.h>

// Problem constants (fixed by the reference)
#define B_ 4
#define T_ 512
#define L_ 15
#define D_ 2048
#define H_ 1024
#define TL_ (T_*L_)            // 7680
#define M_ (B_*TL_)            // 30720
#define K_SPANS 205
#define NSORT 8192
#define NPART 16               // score partials = H/64 column blocks

// d_out float offsets (outputs concatenated flat in return order)
#define OFF_PRUNE 0                                   // [B,T,L,1]  30720
#define OFF_TOP   (OFF_PRUNE + M_)                    // [B,K]      820
#define OFF_FVECS (OFF_TOP + B_*K_SPANS)              // [B,K,D]    1679360
#define OFF_FSC   (OFF_FVECS + B_*K_SPANS*D_)         // [B,K,1]
#define OFF_FBEG  (OFF_FSC + B_*K_SPANS)
#define OFF_FEND  (OFF_FBEG + B_*K_SPANS)
#define OFF_SL    (OFF_FEND + B_*K_SPANS)
#define OFF_SQ    (OFF_SL + B_)
#define OFF_TRI   (OFF_SQ + B_*K_SPANS*K_SPANS)

typedef __attribute__((ext_vector_type(8))) short s16x8;   // 8 bf16 = 4 VGPRs
typedef __attribute__((ext_vector_type(4))) float f32x4;   // MFMA C/D frag

// ---- exact fp32 -> 3x bf16 split helpers (RNE) -----------------------------
__device__ __forceinline__ ushort bf16rne(float f) {
    uint u = __float_as_uint(f);
    return (ushort)((u + 0x7fffu + ((u >> 16) & 1u)) >> 16);
}
__device__ __forceinline__ float bfval(ushort h) {
    return __uint_as_float(((uint)h) << 16);
}
__device__ __forceinline__ void split1(float x, ushort& h0, ushort& h1, ushort& h2) {
    h0 = bf16rne(x);            float f0 = bfval(h0);
    float r = x - f0;           h1 = bf16rne(r);
    float r2 = r - bfval(h1);   h2 = bf16rne(r2);
}
__device__ __forceinline__ void split4(float4 v, uint2& q0, uint2& q1, uint2& q2) {
    ushort a0[4], a1[4], a2[4];
    float x[4] = {v.x, v.y, v.z, v.w};
    #pragma unroll
    for (int j = 0; j < 4; ++j) split1(x[j], a0[j], a1[j], a2[j]);
    q0 = make_uint2((uint)a0[0] | ((uint)a0[1] << 16), (uint)a0[2] | ((uint)a0[3] << 16));
    q1 = make_uint2((uint)a1[0] | ((uint)a1[1] << 16), (uint)a1[2] | ((uint)a1[3] << 16));
    q2 = make_uint2((uint)a2[0] | ((uint)a2[1] << 16), (uint)a2[2] | ((uint)a2[3] << 16));
}

__device__ __forceinline__ f32x4 mfma16(s16x8 a, s16x8 b, f32x4 c) {
    return __builtin_amdgcn_mfma_f32_16x16x32_bf16(a, b, c, 0, 0, 0);
}

// ---------------------------------------------------------------------------
// W pre-split into k-panel layout: P[s][(k8*1024 + n)*8 + j] = split_s(W[k8*8+j][n])
// ---------------------------------------------------------------------------
__global__ void split_w_panel(const float* __restrict__ W, ushort* __restrict__ P0,
                              ushort* __restrict__ P1, ushort* __restrict__ P2, int K8)
{
    const int idx = blockIdx.x * 256 + threadIdx.x;        // (k8, n), N = 1024
    if (idx >= K8 * 1024) return;
    const int k8 = idx >> 10;
    const int n  = idx & 1023;
    ushort h0[8], h1[8], h2[8];
    #pragma unroll
    for (int j = 0; j < 8; ++j) {
        float w = W[(size_t)(k8 * 8 + j) * 1024 + n];
        split1(w, h0[j], h1[j], h2[j]);
    }
    *(uint4*)(P0 + (size_t)idx * 8) = *(uint4*)h0;
    *(uint4*)(P1 + (size_t)idx * 8) = *(uint4*)h1;
    *(uint4*)(P2 + (size_t)idx * 8) = *(uint4*)h2;
}

// ---------------------------------------------------------------------------
// Split-bf16 MFMA GEMM. A [M,KDIM] fp32 row-major (split inline to 3x bf16),
// B = pre-split W panels, N=1024. Block tile 256x64, 4 waves of 64x64,
// 16x16x32 MFMA, 6 products per logical fp32 product (~fp32-exact).
// FUSE=false: out = relu(A@W + bias) fp32 [M,1024]  (h1)
// FUSE=true : out[cb*M + m] = sum_{n in 64-col block cb} relu(h2+b2)[m][n]*W3[n]
// ---------------------------------------------------------------------------
template<int KDIM, bool FUSE>
__global__ __launch_bounds__(256, 2) void gemm_split(
    const float* __restrict__ A,
    const ushort* __restrict__ P0, const ushort* __restrict__ P1,
    const ushort* __restrict__ P2,
    const float* __restrict__ bias, const float* __restrict__ W3,
    float* __restrict__ out)
{
    // padded chunk spaces: A chunks q*257+m (q=0..3, m=0..255), B chunks q*65+n
    __shared__ ushort aLds[3][4 * 257 * 8];   // 3 x 16448 B
    __shared__ ushort bLds[3][4 * 65 * 8];    // 3 x  4160 B   (total 61824 B)

    const int tid   = threadIdx.x;
    const int lane  = tid & 63;
    const int lr    = lane & 15;          // fragment row/col part
    const int lq    = lane >> 4;          // fragment quad (k-group)
    const int waveM = (tid >> 6) * 64;    // 4 waves stacked in m
    const int m0    = blockIdx.y * 256;
    const int n0    = blockIdx.x * 64;

    const int bq = tid >> 6;              // B staging: q group
    const int bn = tid & 63;              //            n_local
    const int ar = tid >> 3;              // A staging: base row (0..31)
    const int ac4 = tid & 7;              //            float4 index in 32-k row

    f32x4 acc[4][4] = {};

    for (int kt = 0; kt < KDIM / 32; ++kt) {
        const int k80 = kt * 4;
        // global loads (B panels are bf16 chunks, A is fp32)
        const size_t bchunk = ((size_t)(k80 + bq) * 1024 + n0 + bn) * 8;
        uint4 bf0 = *(const uint4*)(P0 + bchunk);
        uint4 bf1 = *(const uint4*)(P1 + bchunk);
        uint4 bf2 = *(const uint4*)(P2 + bchunk);
        float4 av[8];
        #pragma unroll
        for (int sw = 0; sw < 8; ++sw) {
            const int row = sw * 32 + ar;
            av[sw] = *(const float4*)(A + (size_t)(m0 + row) * KDIM + kt * 32 + ac4 * 4);
        }
        __syncthreads();   // previous iteration's LDS reads complete
        *(uint4*)&bLds[0][(bq * 65 + bn) * 8] = bf0;
        *(uint4*)&bLds[1][(bq * 65 + bn) * 8] = bf1;
        *(uint4*)&bLds[2][(bq * 65 + bn) * 8] = bf2;
        #pragma unroll
        for (int sw = 0; sw < 8; ++sw) {
            const int row = sw * 32 + ar;
            uint2 q0, q1, q2;
            split4(av[sw], q0, q1, q2);
            const int off = ((ac4 >> 1) * 257 + row) * 8 + (ac4 & 1) * 4;
            *(uint2*)&aLds[0][off] = q0;
            *(uint2*)&aLds[1][off] = q1;
            *(uint2*)&aLds[2][off] = q2;
        }
        __syncthreads();

        s16x8 B0[4], B1[4], B2[4];
        #pragma unroll
        for (int nt = 0; nt < 4; ++nt) {
            const int boff = (lq * 65 + nt * 16 + lr) * 8;
            B0[nt] = *(const s16x8*)&bLds[0][boff];
            B1[nt] = *(const s16x8*)&bLds[1][boff];
            B2[nt] = *(const s16x8*)&bLds[2][boff];
        }
        #pragma unroll
        for (int mt = 0; mt < 4; ++mt) {
            const int aoff = (lq * 257 + waveM + mt * 16 + lr) * 8;
            s16x8 A0 = *(const s16x8*)&aLds[0][aoff];
            s16x8 A1 = *(const s16x8*)&aLds[1][aoff];
            s16x8 A2 = *(const s16x8*)&aLds[2][aoff];
            #pragma unroll
            for (int nt = 0; nt < 4; ++nt) {
                f32x4 c = acc[mt][nt];
                c = mfma16(A0, B0[nt], c);
                c = mfma16(A0, B1[nt], c);
                c = mfma16(A1, B0[nt], c);
                c = mfma16(A1, B1[nt], c);
                c = mfma16(A0, B2[nt], c);
                c = mfma16(A2, B0[nt], c);
                acc[mt][nt] = c;
            }
        }
    }

    // epilogue. C/D layout: col = lane&15, row = (lane>>4)*4 + reg  [m89-verified]
    float bv[4];
    #pragma unroll
    for (int nt = 0; nt < 4; ++nt) bv[nt] = bias[n0 + nt * 16 + lr];

    if (!FUSE) {
        #pragma unroll
        for (int mt = 0; mt < 4; ++mt)
            #pragma unroll
            for (int nt = 0; nt < 4; ++nt)
                #pragma unroll
                for (int r = 0; r < 4; ++r) {
                    const int row = m0 + waveM + mt * 16 + lq * 4 + r;
                    out[(size_t)row * 1024 + n0 + nt * 16 + lr] =
                        fmaxf(acc[mt][nt][r] + bv[nt], 0.f);
                }
    } else {
        float wv[4];
        #pragma unroll
        for (int nt = 0; nt < 4; ++nt) wv[nt] = W3[n0 + nt * 16 + lr];
        #pragma unroll
        for (int mt = 0; mt < 4; ++mt)
            #pragma unroll
            for (int r = 0; r < 4; ++r) {
                float v = 0.f;
                #pragma unroll
                for (int nt = 0; nt < 4; ++nt)
                    v += fmaxf(acc[mt][nt][r] + bv[nt], 0.f) * wv[nt];
                v += __shfl_xor(v, 1);
                v += __shfl_xor(v, 2);
                v += __shfl_xor(v, 4);
                v += __shfl_xor(v, 8);
                if (lr == 0)
                    out[(size_t)blockIdx.x * M_ + m0 + waveM + mt * 16 + lq * 4 + r] = v;
            }
    }
}

// ---------------------------------------------------------------------------
// Top-K per batch (unchanged from R1 except NPART=16 partials)
// ---------------------------------------------------------------------------
__device__ __forceinline__ uint64_t score_key(float s, int idx) {
    unsigned u = __float_as_uint(s);
    u = (u & 0x80000000u) ? ~u : (u | 0x80000000u);
    return ((uint64_t)u << 32) | (uint64_t)(0xFFFFFFFFu - (unsigned)idx);
}

__device__ __forceinline__ float compute_score(
    const float* __restrict__ partial, const float* __restrict__ mask,
    float b3v, int b, int i)
{
    const int m = b * TL_ + i;
    float s = b3v;
    #pragma unroll
    for (int cb = 0; cb < NPART; ++cb) s += partial[(size_t)cb * M_ + m];
    s -= (1.0f - mask[m]) * 10000.0f;
    return s;
}

__global__ __launch_bounds__(1024) void topk_kernel(
    const float* __restrict__ partial, const float* __restrict__ span_mask,
    const int* __restrict__ span_begin, const int* __restrict__ span_end,
    const int* __restrict__ seq_len, const float* __restrict__ b3,
    float* __restrict__ out, int* __restrict__ topk_ws)
{
    __shared__ uint64_t keys[NSORT];
    const int tid = threadIdx.x;
    const int b   = blockIdx.x;
    const float b3v = b3[0];

    for (int i = tid; i < NSORT; i += 1024) {
        if (i < TL_) {
            float s = compute_score(partial, span_mask, b3v, b, i);
            out[OFF_PRUNE + b * TL_ + i] = s;
            keys[i] = score_key(s, i);
        } else {
            keys[i] = 0ull;
        }
    }
    __syncthreads();

    for (unsigned kk = 2; kk <= NSORT; kk <<= 1) {
        for (unsigned j = kk >> 1; j > 0; j >>= 1) {
            for (unsigned i = (unsigned)tid; i < NSORT; i += 1024) {
                unsigned ixj = i ^ j;
                if (ixj > i) {
                    uint64_t x = keys[i], y = keys[ixj];
                    bool desc = ((i & kk) == 0);
                    if (desc ? (x < y) : (x > y)) { keys[i] = y; keys[ixj] = x; }
                }
            }
            __syncthreads();
        }
    }

    const uint64_t cutoff = keys[K_SPANS - 1];
    __syncthreads();

    unsigned* sScan = (unsigned*)keys;
    unsigned base = 0;
    const unsigned lane = tid & 63;
    const unsigned wv   = tid >> 6;
    for (int c = 0; c < TL_; c += 1024) {
        const int i = c + tid;
        bool flag = false; float s = 0.f;
        if (i < TL_) {
            s = compute_score(partial, span_mask, b3v, b, i);
            flag = (score_key(s, i) >= cutoff);
        }
        uint64_t bal = __ballot(flag);
        unsigned pre = (unsigned)__popcll(bal & ((1ull << lane) - 1ull));
        if (lane == 0) sScan[wv] = (unsigned)__popcll(bal);
        __syncthreads();
        unsigned woff = 0, tot = 0;
        for (int w = 0; w < 16; ++w) {
            unsigned v = sScan[w];
            if (w < (int)wv) woff += v;
            tot += v;
        }
        if (flag) {
            const int g = b * K_SPANS + (int)(base + woff + pre);
            topk_ws[g]        = i;
            out[OFF_TOP + g]  = (float)i;
            out[OFF_FSC + g]  = s;
            out[OFF_FBEG + g] = (float)span_begin[b * TL_ + i];
            out[OFF_FEND + g] = (float)span_end[b * TL_ + i];
        }
        base += tot;
        __syncthreads();
    }

    if (tid == 0)
        out[OFF_SL + b] = ceilf(0.4f * (float)seq_len[b]);
}

// ---------------------------------------------------------------------------
__global__ void gather_vecs(const float* __restrict__ span_vecs,
                            const int* __restrict__ topk_ws,
                            float* __restrict__ out)
{
    const int bk  = blockIdx.x;
    const int b   = bk / K_SPANS;
    const int row = topk_ws[bk];
    const float4* src = (const float4*)(span_vecs + ((size_t)b * TL_ + row) * D_);
    float4* dst = (float4*)(out + OFF_FVECS + (size_t)bk * D_);
    for (int j = threadIdx.x; j < D_ / 4; j += blockDim.x) dst[j] = src[j];
}

__global__ void masks_kernel(const int* __restrict__ seq_len,
                             float* __restrict__ out)
{
    const int idx = blockIdx.x * blockDim.x + threadIdx.x;
    if (idx >= B_ * K_SPANS * K_SPANS) return;
    const int b = idx / (K_SPANS * K_SPANS);
    const int r = idx - b * K_SPANS * K_SPANS;
    const int i = r / K_SPANS;
    const int j = r - i * K_SPANS;
    const int sl = (int)ceilf(0.4f * (float)seq_len[b]);
    const float v = (i < sl && j < sl) ? 1.0f : 0.0f;
    out[OFF_SQ + idx]  = v;
    out[OFF_TRI + idx] = (j <= i) ? v : 0.0f;
}

// ---------------------------------------------------------------------------
extern "C" void kernel_launch(void* const* d_in, const int* in_sizes, int n_in,
                              void* d_out, int out_size, void* d_ws, size_t ws_size,
                              hipStream_t stream)
{
    const float* span_vecs  = (const float*)d_in[0];
    const float* span_mask  = (const float*)d_in[1];
    const int*   span_begin = (const int*)  d_in[2];
    const int*   span_end   = (const int*)  d_in[3];
    const int*   seq_len    = (const int*)  d_in[4];
    const float* W1 = (const float*)d_in[5];
    const float* b1 = (const float*)d_in[6];
    const float* W2 = (const float*)d_in[7];
    const float* b2 = (const float*)d_in[8];
    const float* W3 = (const float*)d_in[9];
    const float* b3 = (const float*)d_in[10];
    float* out = (float*)d_out;

    // workspace layout (~147 MB):
    // h1 fp32 [M,1024] | partial [16,M] | W1 panels 3x | W2 panels 3x | topk idx
    float*  h1      = (float*)d_ws;
    float*  partial = h1 + (size_t)M_ * H_;
    ushort* w1p0    = (ushort*)(partial + (size_t)NPART * M_);
    ushort* w1p1    = w1p0 + (size_t)256 * 1024 * 8;     // K8=256 panels
    ushort* w1p2    = w1p1 + (size_t)256 * 1024 * 8;
    ushort* w2p0    = w1p2 + (size_t)256 * 1024 * 8;
    ushort* w2p1    = w2p0 + (size_t)128 * 1024 * 8;     // K8=128 panels
    ushort* w2p2    = w2p1 + (size_t)128 * 1024 * 8;
    int*    topk_ws = (int*)(w2p2 + (size_t)128 * 1024 * 8);

    split_w_panel<<<(256 * 1024) / 256, 256, 0, stream>>>(W1, w1p0, w1p1, w1p2, 256);
    split_w_panel<<<(128 * 1024) / 256, 256, 0, stream>>>(W2, w2p0, w2p1, w2p2, 128);

    // grid.x = n-blocks (fast) so the 16 blocks sharing an A m-panel run together (L2)
    gemm_split<2048, false><<<dim3(16, 120), 256, 0, stream>>>(
        span_vecs, w1p0, w1p1, w1p2, b1, nullptr, h1);
    gemm_split<1024, true><<<dim3(16, 120), 256, 0, stream>>>(
        h1, w2p0, w2p1, w2p2, b2, W3, partial);

    topk_kernel<<<B_, 1024, 0, stream>>>(
        partial, span_mask, span_begin, span_end, seq_len, b3, out, topk_ws);
    gather_vecs<<<B_ * K_SPANS, 256, 0, stream>>>(span_vecs, topk_ws, out);
    masks_kernel<<<(B_ * K_SPANS * K_SPANS + 255) / 256, 256, 0, stream>>>(
        seq_len, out);
}

// Round 3
// 1679.600 us; speedup vs baseline: 1.5831x; 1.0122x over previous
//
#include <hip/hip_runtime.h>
#include <stdint.h>

// Problem constants (fixed by the reference)
#define B_ 4
#define T_ 512
#define L_ 15
#define D_ 2048
#define H_ 1024
#define TL_ (T_*L_)            // 7680
#define M_ (B_*TL_)            // 30720
#define K_SPANS 205
#define NSORT 8192
#define NPART 16               // score partials = H/64 column blocks

// d_out float offsets (outputs concatenated flat in return order)
#define OFF_PRUNE 0                                   // [B,T,L,1]  30720
#define OFF_TOP   (OFF_PRUNE + M_)                    // [B,K]      820
#define OFF_FVECS (OFF_TOP + B_*K_SPANS)              // [B,K,D]    1679360
#define OFF_FSC   (OFF_FVECS + B_*K_SPANS*D_)         // [B,K,1]
#define OFF_FBEG  (OFF_FSC + B_*K_SPANS)
#define OFF_FEND  (OFF_FBEG + B_*K_SPANS)
#define OFF_SL    (OFF_FEND + B_*K_SPANS)
#define OFF_SQ    (OFF_SL + B_)
#define OFF_TRI   (OFF_SQ + B_*K_SPANS*K_SPANS)

typedef __attribute__((ext_vector_type(8))) short s16x8;   // 8 bf16 = 4 VGPRs
typedef __attribute__((ext_vector_type(4))) float f32x4;   // MFMA C/D frag

// ---- exact fp32 -> 3x bf16 split helpers (RNE) -----------------------------
__device__ __forceinline__ ushort bf16rne(float f) {
    uint u = __float_as_uint(f);
    return (ushort)((u + 0x7fffu + ((u >> 16) & 1u)) >> 16);
}
__device__ __forceinline__ float bfval(ushort h) {
    return __uint_as_float(((uint)h) << 16);
}
__device__ __forceinline__ void split1(float x, ushort& h0, ushort& h1, ushort& h2) {
    h0 = bf16rne(x);            float f0 = bfval(h0);
    float r = x - f0;           h1 = bf16rne(r);
    float r2 = r - bfval(h1);   h2 = bf16rne(r2);
}
__device__ __forceinline__ void split4(float4 v, uint2& q0, uint2& q1, uint2& q2) {
    ushort a0[4], a1[4], a2[4];
    float x[4] = {v.x, v.y, v.z, v.w};
    #pragma unroll
    for (int j = 0; j < 4; ++j) split1(x[j], a0[j], a1[j], a2[j]);
    q0 = make_uint2((uint)a0[0] | ((uint)a0[1] << 16), (uint)a0[2] | ((uint)a0[3] << 16));
    q1 = make_uint2((uint)a1[0] | ((uint)a1[1] << 16), (uint)a1[2] | ((uint)a1[3] << 16));
    q2 = make_uint2((uint)a2[0] | ((uint)a2[1] << 16), (uint)a2[2] | ((uint)a2[3] << 16));
}

__device__ __forceinline__ f32x4 mfma16(s16x8 a, s16x8 b, f32x4 c) {
    return __builtin_amdgcn_mfma_f32_16x16x32_bf16(a, b, c, 0, 0, 0);
}

// ===========================================================================
// FAST PATH (needs ~713 MB ws)
// Panels are stored in MFMA fragment-tile layout:
//   tile = (row16_idx * K32 + g), 1024 B per tile,
//   lane l (l=0..63) owns 8 bf16 at tile*1024 + l*16:
//     A-panel: A[row16*16 + (l&15)][g*32 + (l>>4)*8 + j]
//     B-panel: W[g*32 + (l>>4)*8 + j][n16*16 + (l&15)]
// so a wave loads a whole fragment with ONE coalesced dwordx4 at voffs l*16.
// ===========================================================================

// A [ROWS, K32*32] fp32 row-major -> 3 split panels in frag-tile layout.
// 4 waves per block = 4 consecutive g of the same row16 (L1/L2 line reuse).
template<int K32>
__global__ __launch_bounds__(256) void split_a_panel(
    const float* __restrict__ A, ushort* __restrict__ P0,
    ushort* __restrict__ P1, ushort* __restrict__ P2)
{
    const int l    = threadIdx.x & 63;
    const int w    = threadIdx.x >> 6;
    const int tile = blockIdx.x * 4 + w;
    const int r16  = tile / K32;
    const int g    = tile % K32;
    const int row  = r16 * 16 + (l & 15);
    const int k0   = g * 32 + (l >> 4) * 8;
    const float* src = A + (size_t)row * (K32 * 32) + k0;
    float4 v0 = *(const float4*)src;
    float4 v1 = *(const float4*)(src + 4);
    uint2 a0, a1, a2, b0, b1, b2;
    split4(v0, a0, a1, a2);
    split4(v1, b0, b1, b2);
    const size_t off = ((size_t)tile * 64 + l) * 8;
    *(uint4*)(P0 + off) = make_uint4(a0.x, a0.y, b0.x, b0.y);
    *(uint4*)(P1 + off) = make_uint4(a1.x, a1.y, b1.x, b1.y);
    *(uint4*)(P2 + off) = make_uint4(a2.x, a2.y, b2.x, b2.y);
}

// W [K32*32, 1024] fp32 -> 3 split panels in frag-tile layout (B-operand).
template<int K32>
__global__ __launch_bounds__(256) void split_w_frag(
    const float* __restrict__ W, ushort* __restrict__ P0,
    ushort* __restrict__ P1, ushort* __restrict__ P2)
{
    const int idx  = blockIdx.x * 256 + threadIdx.x;
    const int l    = idx & 63;
    const int tile = idx >> 6;
    const int n16  = tile / K32;
    const int g    = tile % K32;
    const int n    = n16 * 16 + (l & 15);
    const int kb   = g * 32 + (l >> 4) * 8;
    ushort h0[8], h1[8], h2[8];
    #pragma unroll
    for (int j = 0; j < 8; ++j) {
        float wv = W[(size_t)(kb + j) * 1024 + n];
        split1(wv, h0[j], h1[j], h2[j]);
    }
    const size_t off = (size_t)idx * 8;
    *(uint4*)(P0 + off) = *(uint4*)h0;
    *(uint4*)(P1 + off) = *(uint4*)h1;
    *(uint4*)(P2 + off) = *(uint4*)h2;
}

// LDS-free split-bf16 MFMA GEMM. All fragments loaded straight from panels.
// Block = 4 waves stacked in m; wave tile 64m x 64n; 96 MFMA per k32 step.
template<int K32, bool FUSE>
__global__ __launch_bounds__(256, 2) void gemm_frag(
    const ushort* __restrict__ Ap0, const ushort* __restrict__ Ap1,
    const ushort* __restrict__ Ap2,
    const ushort* __restrict__ Bp0, const ushort* __restrict__ Bp1,
    const ushort* __restrict__ Bp2,
    const float* __restrict__ bias, const float* __restrict__ W3,
    float* __restrict__ out)
{
    const int tid = threadIdx.x;
    const int l   = tid & 63;
    const int w   = tid >> 6;
    const int lr  = l & 15;
    const int lq  = l >> 4;
    const int mb  = blockIdx.y * 16 + w * 4;   // base m16-tile (4 per wave)
    const int nb  = blockIdx.x * 4;            // base n16-tile
    const int n0  = blockIdx.x * 64;

    size_t aoff[4], boff[4];
    #pragma unroll
    for (int t = 0; t < 4; ++t) {
        aoff[t] = ((size_t)(mb + t) * K32 * 64 + l) * 8;
        boff[t] = ((size_t)(nb + t) * K32 * 64 + l) * 8;
    }

    f32x4 acc[4][4] = {};

    for (int g = 0; g < K32; ++g) {
        s16x8 A0[4], A1[4], A2[4], B0[4], B1[4], B2[4];
        const size_t gofs = (size_t)g * 512;
        #pragma unroll
        for (int t = 0; t < 4; ++t) {
            const size_t ao = aoff[t] + gofs;
            const size_t bo = boff[t] + gofs;
            A0[t] = *(const s16x8*)(Ap0 + ao);
            A1[t] = *(const s16x8*)(Ap1 + ao);
            A2[t] = *(const s16x8*)(Ap2 + ao);
            B0[t] = *(const s16x8*)(Bp0 + bo);
            B1[t] = *(const s16x8*)(Bp1 + bo);
            B2[t] = *(const s16x8*)(Bp2 + bo);
        }
        #pragma unroll
        for (int mt = 0; mt < 4; ++mt)
            #pragma unroll
            for (int nt = 0; nt < 4; ++nt) {
                f32x4 c = acc[mt][nt];
                c = mfma16(A0[mt], B0[nt], c);
                c = mfma16(A0[mt], B1[nt], c);
                c = mfma16(A1[mt], B0[nt], c);
                c = mfma16(A1[mt], B1[nt], c);
                c = mfma16(A0[mt], B2[nt], c);
                c = mfma16(A2[mt], B0[nt], c);
                acc[mt][nt] = c;
            }
    }

    // C/D layout: col = lane&15, row = (lane>>4)*4 + reg  [m89-verified]
    float bv[4];
    #pragma unroll
    for (int nt = 0; nt < 4; ++nt) bv[nt] = bias[n0 + nt * 16 + lr];

    if (!FUSE) {
        #pragma unroll
        for (int mt = 0; mt < 4; ++mt)
            #pragma unroll
            for (int nt = 0; nt < 4; ++nt)
                #pragma unroll
                for (int r = 0; r < 4; ++r) {
                    const int row = (mb + mt) * 16 + lq * 4 + r;
                    out[(size_t)row * 1024 + n0 + nt * 16 + lr] =
                        fmaxf(acc[mt][nt][r] + bv[nt], 0.f);
                }
    } else {
        float wv[4];
        #pragma unroll
        for (int nt = 0; nt < 4; ++nt) wv[nt] = W3[n0 + nt * 16 + lr];
        #pragma unroll
        for (int mt = 0; mt < 4; ++mt)
            #pragma unroll
            for (int r = 0; r < 4; ++r) {
                float v = 0.f;
                #pragma unroll
                for (int nt = 0; nt < 4; ++nt)
                    v += fmaxf(acc[mt][nt][r] + bv[nt], 0.f) * wv[nt];
                v += __shfl_xor(v, 1);
                v += __shfl_xor(v, 2);
                v += __shfl_xor(v, 4);
                v += __shfl_xor(v, 8);
                if (lr == 0)
                    out[(size_t)blockIdx.x * M_ + (mb + mt) * 16 + lq * 4 + r] = v;
            }
    }
}

// ===========================================================================
// FALLBACK PATH (R2, ~147 MB ws) — unchanged, proven correct.
// ===========================================================================
__global__ void split_w_panel(const float* __restrict__ W, ushort* __restrict__ P0,
                              ushort* __restrict__ P1, ushort* __restrict__ P2, int K8)
{
    const int idx = blockIdx.x * 256 + threadIdx.x;
    if (idx >= K8 * 1024) return;
    const int k8 = idx >> 10;
    const int n  = idx & 1023;
    ushort h0[8], h1[8], h2[8];
    #pragma unroll
    for (int j = 0; j < 8; ++j) {
        float w = W[(size_t)(k8 * 8 + j) * 1024 + n];
        split1(w, h0[j], h1[j], h2[j]);
    }
    *(uint4*)(P0 + (size_t)idx * 8) = *(uint4*)h0;
    *(uint4*)(P1 + (size_t)idx * 8) = *(uint4*)h1;
    *(uint4*)(P2 + (size_t)idx * 8) = *(uint4*)h2;
}

template<int KDIM, bool FUSE>
__global__ __launch_bounds__(256, 2) void gemm_split(
    const float* __restrict__ A,
    const ushort* __restrict__ P0, const ushort* __restrict__ P1,
    const ushort* __restrict__ P2,
    const float* __restrict__ bias, const float* __restrict__ W3,
    float* __restrict__ out)
{
    __shared__ ushort aLds[3][4 * 257 * 8];
    __shared__ ushort bLds[3][4 * 65 * 8];

    const int tid   = threadIdx.x;
    const int lane  = tid & 63;
    const int lr    = lane & 15;
    const int lq    = lane >> 4;
    const int waveM = (tid >> 6) * 64;
    const int m0    = blockIdx.y * 256;
    const int n0    = blockIdx.x * 64;

    const int bq = tid >> 6;
    const int bn = tid & 63;
    const int ar = tid >> 3;
    const int ac4 = tid & 7;

    f32x4 acc[4][4] = {};

    for (int kt = 0; kt < KDIM / 32; ++kt) {
        const int k80 = kt * 4;
        const size_t bchunk = ((size_t)(k80 + bq) * 1024 + n0 + bn) * 8;
        uint4 bf0 = *(const uint4*)(P0 + bchunk);
        uint4 bf1 = *(const uint4*)(P1 + bchunk);
        uint4 bf2 = *(const uint4*)(P2 + bchunk);
        float4 av[8];
        #pragma unroll
        for (int sw = 0; sw < 8; ++sw) {
            const int row = sw * 32 + ar;
            av[sw] = *(const float4*)(A + (size_t)(m0 + row) * KDIM + kt * 32 + ac4 * 4);
        }
        __syncthreads();
        *(uint4*)&bLds[0][(bq * 65 + bn) * 8] = bf0;
        *(uint4*)&bLds[1][(bq * 65 + bn) * 8] = bf1;
        *(uint4*)&bLds[2][(bq * 65 + bn) * 8] = bf2;
        #pragma unroll
        for (int sw = 0; sw < 8; ++sw) {
            const int row = sw * 32 + ar;
            uint2 q0, q1, q2;
            split4(av[sw], q0, q1, q2);
            const int off = ((ac4 >> 1) * 257 + row) * 8 + (ac4 & 1) * 4;
            *(uint2*)&aLds[0][off] = q0;
            *(uint2*)&aLds[1][off] = q1;
            *(uint2*)&aLds[2][off] = q2;
        }
        __syncthreads();

        s16x8 B0[4], B1[4], B2[4];
        #pragma unroll
        for (int nt = 0; nt < 4; ++nt) {
            const int boff = (lq * 65 + nt * 16 + lr) * 8;
            B0[nt] = *(const s16x8*)&bLds[0][boff];
            B1[nt] = *(const s16x8*)&bLds[1][boff];
            B2[nt] = *(const s16x8*)&bLds[2][boff];
        }
        #pragma unroll
        for (int mt = 0; mt < 4; ++mt) {
            const int aoff = (lq * 257 + waveM + mt * 16 + lr) * 8;
            s16x8 A0 = *(const s16x8*)&aLds[0][aoff];
            s16x8 A1 = *(const s16x8*)&aLds[1][aoff];
            s16x8 A2 = *(const s16x8*)&aLds[2][aoff];
            #pragma unroll
            for (int nt = 0; nt < 4; ++nt) {
                f32x4 c = acc[mt][nt];
                c = mfma16(A0, B0[nt], c);
                c = mfma16(A0, B1[nt], c);
                c = mfma16(A1, B0[nt], c);
                c = mfma16(A1, B1[nt], c);
                c = mfma16(A0, B2[nt], c);
                c = mfma16(A2, B0[nt], c);
                acc[mt][nt] = c;
            }
        }
    }

    float bv[4];
    #pragma unroll
    for (int nt = 0; nt < 4; ++nt) bv[nt] = bias[n0 + nt * 16 + lr];

    if (!FUSE) {
        #pragma unroll
        for (int mt = 0; mt < 4; ++mt)
            #pragma unroll
            for (int nt = 0; nt < 4; ++nt)
                #pragma unroll
                for (int r = 0; r < 4; ++r) {
                    const int row = m0 + waveM + mt * 16 + lq * 4 + r;
                    out[(size_t)row * 1024 + n0 + nt * 16 + lr] =
                        fmaxf(acc[mt][nt][r] + bv[nt], 0.f);
                }
    } else {
        float wv[4];
        #pragma unroll
        for (int nt = 0; nt < 4; ++nt) wv[nt] = W3[n0 + nt * 16 + lr];
        #pragma unroll
        for (int mt = 0; mt < 4; ++mt)
            #pragma unroll
            for (int r = 0; r < 4; ++r) {
                float v = 0.f;
                #pragma unroll
                for (int nt = 0; nt < 4; ++nt)
                    v += fmaxf(acc[mt][nt][r] + bv[nt], 0.f) * wv[nt];
                v += __shfl_xor(v, 1);
                v += __shfl_xor(v, 2);
                v += __shfl_xor(v, 4);
                v += __shfl_xor(v, 8);
                if (lr == 0)
                    out[(size_t)blockIdx.x * M_ + m0 + waveM + mt * 16 + lq * 4 + r] = v;
            }
    }
}

// ===========================================================================
// Top-K / gather / masks (shared by both paths)
// ===========================================================================
__device__ __forceinline__ uint64_t score_key(float s, int idx) {
    unsigned u = __float_as_uint(s);
    u = (u & 0x80000000u) ? ~u : (u | 0x80000000u);
    return ((uint64_t)u << 32) | (uint64_t)(0xFFFFFFFFu - (unsigned)idx);
}

__device__ __forceinline__ float compute_score(
    const float* __restrict__ partial, const float* __restrict__ mask,
    float b3v, int b, int i)
{
    const int m = b * TL_ + i;
    float s = b3v;
    #pragma unroll
    for (int cb = 0; cb < NPART; ++cb) s += partial[(size_t)cb * M_ + m];
    s -= (1.0f - mask[m]) * 10000.0f;
    return s;
}

__global__ __launch_bounds__(1024) void topk_kernel(
    const float* __restrict__ partial, const float* __restrict__ span_mask,
    const int* __restrict__ span_begin, const int* __restrict__ span_end,
    const int* __restrict__ seq_len, const float* __restrict__ b3,
    float* __restrict__ out, int* __restrict__ topk_ws)
{
    __shared__ uint64_t keys[NSORT];
    const int tid = threadIdx.x;
    const int b   = blockIdx.x;
    const float b3v = b3[0];

    for (int i = tid; i < NSORT; i += 1024) {
        if (i < TL_) {
            float s = compute_score(partial, span_mask, b3v, b, i);
            out[OFF_PRUNE + b * TL_ + i] = s;
            keys[i] = score_key(s, i);
        } else {
            keys[i] = 0ull;
        }
    }
    __syncthreads();

    for (unsigned kk = 2; kk <= NSORT; kk <<= 1) {
        for (unsigned j = kk >> 1; j > 0; j >>= 1) {
            for (unsigned i = (unsigned)tid; i < NSORT; i += 1024) {
                unsigned ixj = i ^ j;
                if (ixj > i) {
                    uint64_t x = keys[i], y = keys[ixj];
                    bool desc = ((i & kk) == 0);
                    if (desc ? (x < y) : (x > y)) { keys[i] = y; keys[ixj] = x; }
                }
            }
            __syncthreads();
        }
    }

    const uint64_t cutoff = keys[K_SPANS - 1];
    __syncthreads();

    unsigned* sScan = (unsigned*)keys;
    unsigned base = 0;
    const unsigned lane = tid & 63;
    const unsigned wv   = tid >> 6;
    for (int c = 0; c < TL_; c += 1024) {
        const int i = c + tid;
        bool flag = false; float s = 0.f;
        if (i < TL_) {
            s = compute_score(partial, span_mask, b3v, b, i);
            flag = (score_key(s, i) >= cutoff);
        }
        uint64_t bal = __ballot(flag);
        unsigned pre = (unsigned)__popcll(bal & ((1ull << lane) - 1ull));
        if (lane == 0) sScan[wv] = (unsigned)__popcll(bal);
        __syncthreads();
        unsigned woff = 0, tot = 0;
        for (int w = 0; w < 16; ++w) {
            unsigned v = sScan[w];
            if (w < (int)wv) woff += v;
            tot += v;
        }
        if (flag) {
            const int g = b * K_SPANS + (int)(base + woff + pre);
            topk_ws[g]        = i;
            out[OFF_TOP + g]  = (float)i;
            out[OFF_FSC + g]  = s;
            out[OFF_FBEG + g] = (float)span_begin[b * TL_ + i];
            out[OFF_FEND + g] = (float)span_end[b * TL_ + i];
        }
        base += tot;
        __syncthreads();
    }

    if (tid == 0)
        out[OFF_SL + b] = ceilf(0.4f * (float)seq_len[b]);
}

__global__ void gather_vecs(const float* __restrict__ span_vecs,
                            const int* __restrict__ topk_ws,
                            float* __restrict__ out)
{
    const int bk  = blockIdx.x;
    const int b   = bk / K_SPANS;
    const int row = topk_ws[bk];
    const float4* src = (const float4*)(span_vecs + ((size_t)b * TL_ + row) * D_);
    float4* dst = (float4*)(out + OFF_FVECS + (size_t)bk * D_);
    for (int j = threadIdx.x; j < D_ / 4; j += blockDim.x) dst[j] = src[j];
}

__global__ void masks_kernel(const int* __restrict__ seq_len,
                             float* __restrict__ out)
{
    const int idx = blockIdx.x * blockDim.x + threadIdx.x;
    if (idx >= B_ * K_SPANS * K_SPANS) return;
    const int b = idx / (K_SPANS * K_SPANS);
    const int r = idx - b * K_SPANS * K_SPANS;
    const int i = r / K_SPANS;
    const int j = r - i * K_SPANS;
    const int sl = (int)ceilf(0.4f * (float)seq_len[b]);
    const float v = (i < sl && j < sl) ? 1.0f : 0.0f;
    out[OFF_SQ + idx]  = v;
    out[OFF_TRI + idx] = (j <= i) ? v : 0.0f;
}

// ===========================================================================
extern "C" void kernel_launch(void* const* d_in, const int* in_sizes, int n_in,
                              void* d_out, int out_size, void* d_ws, size_t ws_size,
                              hipStream_t stream)
{
    const float* span_vecs  = (const float*)d_in[0];
    const float* span_mask  = (const float*)d_in[1];
    const int*   span_begin = (const int*)  d_in[2];
    const int*   span_end   = (const int*)  d_in[3];
    const int*   seq_len    = (const int*)  d_in[4];
    const float* W1 = (const float*)d_in[5];
    const float* b1 = (const float*)d_in[6];
    const float* W2 = (const float*)d_in[7];
    const float* b2 = (const float*)d_in[8];
    const float* W3 = (const float*)d_in[9];
    const float* b3 = (const float*)d_in[10];
    float* out = (float*)d_out;

    const size_t A1CH = (size_t)M_ * D_;        // ushorts per A1 panel chunk
    const size_t H1CH = (size_t)M_ * H_;        // ushorts per h1 panel chunk
    const size_t W1CH = (size_t)D_ * H_;        // ushorts per W1 panel chunk
    const size_t W2CH = (size_t)H_ * H_;        // ushorts per W2 panel chunk
    const size_t FAST_NEED =
        3 * A1CH * 2 + (size_t)M_ * H_ * 4 + 3 * H1CH * 2 +
        3 * W1CH * 2 + 3 * W2CH * 2 + (size_t)NPART * M_ * 4 + 4096;

    float* partial;
    int*   topk_ws;

    if (ws_size >= FAST_NEED) {
        // ---------------- fast path: LDS-free fragment-panel GEMMs ----------
        char* p = (char*)d_ws;
        ushort* a1p0 = (ushort*)p;  p += A1CH * 2;
        ushort* a1p1 = (ushort*)p;  p += A1CH * 2;
        ushort* a1p2 = (ushort*)p;  p += A1CH * 2;
        float*  h1   = (float*)p;   p += (size_t)M_ * H_ * 4;
        ushort* h1p0 = (ushort*)p;  p += H1CH * 2;
        ushort* h1p1 = (ushort*)p;  p += H1CH * 2;
        ushort* h1p2 = (ushort*)p;  p += H1CH * 2;
        ushort* w1p0 = (ushort*)p;  p += W1CH * 2;
        ushort* w1p1 = (ushort*)p;  p += W1CH * 2;
        ushort* w1p2 = (ushort*)p;  p += W1CH * 2;
        ushort* w2p0 = (ushort*)p;  p += W2CH * 2;
        ushort* w2p1 = (ushort*)p;  p += W2CH * 2;
        ushort* w2p2 = (ushort*)p;  p += W2CH * 2;
        partial      = (float*)p;   p += (size_t)NPART * M_ * 4;
        topk_ws      = (int*)p;

        split_a_panel<64><<<(M_ / 16) * 64 / 4, 256, 0, stream>>>(
            span_vecs, a1p0, a1p1, a1p2);
        split_w_frag<64><<<(H_ / 16) * 64 * 64 / 256, 256, 0, stream>>>(
            W1, w1p0, w1p1, w1p2);
        split_w_frag<32><<<(H_ / 16) * 32 * 64 / 256, 256, 0, stream>>>(
            W2, w2p0, w2p1, w2p2);

        gemm_frag<64, false><<<dim3(16, M_ / 256), 256, 0, stream>>>(
            a1p0, a1p1, a1p2, w1p0, w1p1, w1p2, b1, nullptr, h1);
        split_a_panel<32><<<(M_ / 16) * 32 / 4, 256, 0, stream>>>(
            h1, h1p0, h1p1, h1p2);
        gemm_frag<32, true><<<dim3(16, M_ / 256), 256, 0, stream>>>(
            h1p0, h1p1, h1p2, w2p0, w2p1, w2p2, b2, W3, partial);
    } else {
        // ---------------- fallback: R2 path (proven, ~147 MB) ---------------
        float*  h1   = (float*)d_ws;
        partial      = h1 + (size_t)M_ * H_;
        ushort* w1p0 = (ushort*)(partial + (size_t)NPART * M_);
        ushort* w1p1 = w1p0 + (size_t)256 * 1024 * 8;
        ushort* w1p2 = w1p1 + (size_t)256 * 1024 * 8;
        ushort* w2p0 = w1p2 + (size_t)256 * 1024 * 8;
        ushort* w2p1 = w2p0 + (size_t)128 * 1024 * 8;
        ushort* w2p2 = w2p1 + (size_t)128 * 1024 * 8;
        topk_ws      = (int*)(w2p2 + (size_t)128 * 1024 * 8);

        split_w_panel<<<(256 * 1024) / 256, 256, 0, stream>>>(W1, w1p0, w1p1, w1p2, 256);
        split_w_panel<<<(128 * 1024) / 256, 256, 0, stream>>>(W2, w2p0, w2p1, w2p2, 128);
        gemm_split<2048, false><<<dim3(16, 120), 256, 0, stream>>>(
            span_vecs, w1p0, w1p1, w1p2, b1, nullptr, h1);
        gemm_split<1024, true><<<dim3(16, 120), 256, 0, stream>>>(
            h1, w2p0, w2p1, w2p2, b2, W3, partial);
    }

    topk_kernel<<<B_, 1024, 0, stream>>>(
        partial, span_mask, span_begin, span_end, seq_len, b3, out, topk_ws);
    gather_vecs<<<B_ * K_SPANS, 256, 0, stream>>>(span_vecs, topk_ws, out);
    masks_kernel<<<(B_ * K_SPANS * K_SPANS + 255) / 256, 256, 0, stream>>>(
        seq_len, out);
}

// Round 4
// 1658.377 us; speedup vs baseline: 1.6034x; 1.0128x over previous
//
#include <hip/hip_runtime.h>
#include <stdint.h>

// Problem constants (fixed by the reference)
#define B_ 4
#define T_ 512
#define L_ 15
#define D_ 2048
#define H_ 1024
#define TL_ (T_*L_)            // 7680
#define M_ (B_*TL_)            // 30720
#define K_SPANS 205
#define NSORT 8192
#define NPART 16               // score partials = H/64 column blocks

// d_out float offsets (outputs concatenated flat in return order)
#define OFF_PRUNE 0                                   // [B,T,L,1]  30720
#define OFF_TOP   (OFF_PRUNE + M_)                    // [B,K]      820
#define OFF_FVECS (OFF_TOP + B_*K_SPANS)              // [B,K,D]    1679360
#define OFF_FSC   (OFF_FVECS + B_*K_SPANS*D_)         // [B,K,1]
#define OFF_FBEG  (OFF_FSC + B_*K_SPANS)
#define OFF_FEND  (OFF_FBEG + B_*K_SPANS)
#define OFF_SL    (OFF_FEND + B_*K_SPANS)
#define OFF_SQ    (OFF_SL + B_)
#define OFF_TRI   (OFF_SQ + B_*K_SPANS*K_SPANS)

typedef __attribute__((ext_vector_type(8))) short s16x8;   // 8 bf16 = 4 VGPRs
typedef __attribute__((ext_vector_type(4))) float f32x4;   // MFMA C/D frag

// ---- exact fp32 -> 3x bf16 split helpers (RNE) -----------------------------
__device__ __forceinline__ ushort bf16rne(float f) {
    uint u = __float_as_uint(f);
    return (ushort)((u + 0x7fffu + ((u >> 16) & 1u)) >> 16);
}
__device__ __forceinline__ float bfval(ushort h) {
    return __uint_as_float(((uint)h) << 16);
}
__device__ __forceinline__ void split1(float x, ushort& h0, ushort& h1, ushort& h2) {
    h0 = bf16rne(x);            float f0 = bfval(h0);
    float r = x - f0;           h1 = bf16rne(r);
    float r2 = r - bfval(h1);   h2 = bf16rne(r2);
}
__device__ __forceinline__ void split4(float4 v, uint2& q0, uint2& q1, uint2& q2) {
    ushort a0[4], a1[4], a2[4];
    float x[4] = {v.x, v.y, v.z, v.w};
    #pragma unroll
    for (int j = 0; j < 4; ++j) split1(x[j], a0[j], a1[j], a2[j]);
    q0 = make_uint2((uint)a0[0] | ((uint)a0[1] << 16), (uint)a0[2] | ((uint)a0[3] << 16));
    q1 = make_uint2((uint)a1[0] | ((uint)a1[1] << 16), (uint)a1[2] | ((uint)a1[3] << 16));
    q2 = make_uint2((uint)a2[0] | ((uint)a2[1] << 16), (uint)a2[2] | ((uint)a2[3] << 16));
}

__device__ __forceinline__ f32x4 mfma16(s16x8 a, s16x8 b, f32x4 c) {
    return __builtin_amdgcn_mfma_f32_16x16x32_bf16(a, b, c, 0, 0, 0);
}

// ===========================================================================
// FAST PATH (needs ~713 MB ws)
// Panels are stored in MFMA fragment-tile layout:
//   tile = (row16_idx * K32 + g), 1024 B per tile,
//   lane l (l=0..63) owns 8 bf16 at tile*1024 + l*16:
//     A-panel: A[row16*16 + (l&15)][g*32 + (l>>4)*8 + j]
//     B-panel: W[g*32 + (l>>4)*8 + j][n16*16 + (l&15)]
// so a wave loads a whole fragment with ONE coalesced dwordx4 at voffs l*16.
// ===========================================================================

// A [ROWS, K32*32] fp32 row-major -> 3 split panels in frag-tile layout.
template<int K32>
__global__ __launch_bounds__(256) void split_a_panel(
    const float* __restrict__ A, ushort* __restrict__ P0,
    ushort* __restrict__ P1, ushort* __restrict__ P2)
{
    const int l    = threadIdx.x & 63;
    const int w    = threadIdx.x >> 6;
    const int tile = blockIdx.x * 4 + w;
    const int r16  = tile / K32;
    const int g    = tile % K32;
    const int row  = r16 * 16 + (l & 15);
    const int k0   = g * 32 + (l >> 4) * 8;
    const float* src = A + (size_t)row * (K32 * 32) + k0;
    float4 v0 = *(const float4*)src;
    float4 v1 = *(const float4*)(src + 4);
    uint2 a0, a1, a2, b0, b1, b2;
    split4(v0, a0, a1, a2);
    split4(v1, b0, b1, b2);
    const size_t off = ((size_t)tile * 64 + l) * 8;
    *(uint4*)(P0 + off) = make_uint4(a0.x, a0.y, b0.x, b0.y);
    *(uint4*)(P1 + off) = make_uint4(a1.x, a1.y, b1.x, b1.y);
    *(uint4*)(P2 + off) = make_uint4(a2.x, a2.y, b2.x, b2.y);
}

// W [K32*32, 1024] fp32 -> 3 split panels in frag-tile layout (B-operand).
template<int K32>
__global__ __launch_bounds__(256) void split_w_frag(
    const float* __restrict__ W, ushort* __restrict__ P0,
    ushort* __restrict__ P1, ushort* __restrict__ P2)
{
    const int idx  = blockIdx.x * 256 + threadIdx.x;
    const int l    = idx & 63;
    const int tile = idx >> 6;
    const int n16  = tile / K32;
    const int g    = tile % K32;
    const int n    = n16 * 16 + (l & 15);
    const int kb   = g * 32 + (l >> 4) * 8;
    ushort h0[8], h1[8], h2[8];
    #pragma unroll
    for (int j = 0; j < 8; ++j) {
        float wv = W[(size_t)(kb + j) * 1024 + n];
        split1(wv, h0[j], h1[j], h2[j]);
    }
    const size_t off = (size_t)idx * 8;
    *(uint4*)(P0 + off) = *(uint4*)h0;
    *(uint4*)(P1 + off) = *(uint4*)h1;
    *(uint4*)(P2 + off) = *(uint4*)h2;
}

// LDS-free split-bf16 MFMA GEMM, fragments straight from panels.
// Block = 4 waves stacked in m; wave tile 64m x 64n; 96 MFMA per k32 step.
// k-loop PHASE ROTATION per wave/block de-convoys co-resident waves so one
// wave's MFMA burst covers another's load window (g-order is math-irrelevant).
template<int K32, bool FUSE>
__global__ __launch_bounds__(256, 2) void gemm_frag(
    const ushort* __restrict__ Ap0, const ushort* __restrict__ Ap1,
    const ushort* __restrict__ Ap2,
    const ushort* __restrict__ Bp0, const ushort* __restrict__ Bp1,
    const ushort* __restrict__ Bp2,
    const float* __restrict__ bias, const float* __restrict__ W3,
    float* __restrict__ out)
{
    const int tid = threadIdx.x;
    const int l   = tid & 63;
    const int w   = tid >> 6;
    const int lr  = l & 15;
    const int lq  = l >> 4;
    const int mb  = blockIdx.y * 16 + w * 4;   // base m16-tile (4 per wave)
    const int nb  = blockIdx.x * 4;            // base n16-tile
    const int n0  = blockIdx.x * 64;

    size_t aoff[4], boff[4];
    #pragma unroll
    for (int t = 0; t < 4; ++t) {
        aoff[t] = ((size_t)(mb + t) * K32 * 64 + l) * 8;
        boff[t] = ((size_t)(nb + t) * K32 * 64 + l) * 8;
    }

    f32x4 acc[4][4] = {};

    const int rot = ((w + blockIdx.x + blockIdx.y) & 3) * (K32 / 4);

    for (int gi = 0; gi < K32; ++gi) {
        int g = gi + rot;
        g -= (g >= K32) ? K32 : 0;
        s16x8 A0[4], A1[4], A2[4], B0[4], B1[4], B2[4];
        const size_t gofs = (size_t)g * 512;
        #pragma unroll
        for (int t = 0; t < 4; ++t) {
            const size_t ao = aoff[t] + gofs;
            const size_t bo = boff[t] + gofs;
            A0[t] = *(const s16x8*)(Ap0 + ao);
            A1[t] = *(const s16x8*)(Ap1 + ao);
            A2[t] = *(const s16x8*)(Ap2 + ao);
            B0[t] = *(const s16x8*)(Bp0 + bo);
            B1[t] = *(const s16x8*)(Bp1 + bo);
            B2[t] = *(const s16x8*)(Bp2 + bo);
        }
        #pragma unroll
        for (int mt = 0; mt < 4; ++mt)
            #pragma unroll
            for (int nt = 0; nt < 4; ++nt) {
                f32x4 c = acc[mt][nt];
                c = mfma16(A0[mt], B0[nt], c);
                c = mfma16(A0[mt], B1[nt], c);
                c = mfma16(A1[mt], B0[nt], c);
                c = mfma16(A1[mt], B1[nt], c);
                c = mfma16(A0[mt], B2[nt], c);
                c = mfma16(A2[mt], B0[nt], c);
                acc[mt][nt] = c;
            }
    }

    // C/D layout: col = lane&15, row = (lane>>4)*4 + reg  [m89-verified]
    float bv[4];
    #pragma unroll
    for (int nt = 0; nt < 4; ++nt) bv[nt] = bias[n0 + nt * 16 + lr];

    if (!FUSE) {
        #pragma unroll
        for (int mt = 0; mt < 4; ++mt)
            #pragma unroll
            for (int nt = 0; nt < 4; ++nt)
                #pragma unroll
                for (int r = 0; r < 4; ++r) {
                    const int row = (mb + mt) * 16 + lq * 4 + r;
                    out[(size_t)row * 1024 + n0 + nt * 16 + lr] =
                        fmaxf(acc[mt][nt][r] + bv[nt], 0.f);
                }
    } else {
        float wv[4];
        #pragma unroll
        for (int nt = 0; nt < 4; ++nt) wv[nt] = W3[n0 + nt * 16 + lr];
        #pragma unroll
        for (int mt = 0; mt < 4; ++mt)
            #pragma unroll
            for (int r = 0; r < 4; ++r) {
                float v = 0.f;
                #pragma unroll
                for (int nt = 0; nt < 4; ++nt)
                    v += fmaxf(acc[mt][nt][r] + bv[nt], 0.f) * wv[nt];
                v += __shfl_xor(v, 1);
                v += __shfl_xor(v, 2);
                v += __shfl_xor(v, 4);
                v += __shfl_xor(v, 8);
                if (lr == 0)
                    out[(size_t)blockIdx.x * M_ + (mb + mt) * 16 + lq * 4 + r] = v;
            }
    }
}

// ===========================================================================
// FALLBACK PATH (R2, ~147 MB ws) — unchanged, proven correct.
// ===========================================================================
__global__ void split_w_panel(const float* __restrict__ W, ushort* __restrict__ P0,
                              ushort* __restrict__ P1, ushort* __restrict__ P2, int K8)
{
    const int idx = blockIdx.x * 256 + threadIdx.x;
    if (idx >= K8 * 1024) return;
    const int k8 = idx >> 10;
    const int n  = idx & 1023;
    ushort h0[8], h1[8], h2[8];
    #pragma unroll
    for (int j = 0; j < 8; ++j) {
        float w = W[(size_t)(k8 * 8 + j) * 1024 + n];
        split1(w, h0[j], h1[j], h2[j]);
    }
    *(uint4*)(P0 + (size_t)idx * 8) = *(uint4*)h0;
    *(uint4*)(P1 + (size_t)idx * 8) = *(uint4*)h1;
    *(uint4*)(P2 + (size_t)idx * 8) = *(uint4*)h2;
}

template<int KDIM, bool FUSE>
__global__ __launch_bounds__(256, 2) void gemm_split(
    const float* __restrict__ A,
    const ushort* __restrict__ P0, const ushort* __restrict__ P1,
    const ushort* __restrict__ P2,
    const float* __restrict__ bias, const float* __restrict__ W3,
    float* __restrict__ out)
{
    __shared__ ushort aLds[3][4 * 257 * 8];
    __shared__ ushort bLds[3][4 * 65 * 8];

    const int tid   = threadIdx.x;
    const int lane  = tid & 63;
    const int lr    = lane & 15;
    const int lq    = lane >> 4;
    const int waveM = (tid >> 6) * 64;
    const int m0    = blockIdx.y * 256;
    const int n0    = blockIdx.x * 64;

    const int bq = tid >> 6;
    const int bn = tid & 63;
    const int ar = tid >> 3;
    const int ac4 = tid & 7;

    f32x4 acc[4][4] = {};

    for (int kt = 0; kt < KDIM / 32; ++kt) {
        const int k80 = kt * 4;
        const size_t bchunk = ((size_t)(k80 + bq) * 1024 + n0 + bn) * 8;
        uint4 bf0 = *(const uint4*)(P0 + bchunk);
        uint4 bf1 = *(const uint4*)(P1 + bchunk);
        uint4 bf2 = *(const uint4*)(P2 + bchunk);
        float4 av[8];
        #pragma unroll
        for (int sw = 0; sw < 8; ++sw) {
            const int row = sw * 32 + ar;
            av[sw] = *(const float4*)(A + (size_t)(m0 + row) * KDIM + kt * 32 + ac4 * 4);
        }
        __syncthreads();
        *(uint4*)&bLds[0][(bq * 65 + bn) * 8] = bf0;
        *(uint4*)&bLds[1][(bq * 65 + bn) * 8] = bf1;
        *(uint4*)&bLds[2][(bq * 65 + bn) * 8] = bf2;
        #pragma unroll
        for (int sw = 0; sw < 8; ++sw) {
            const int row = sw * 32 + ar;
            uint2 q0, q1, q2;
            split4(av[sw], q0, q1, q2);
            const int off = ((ac4 >> 1) * 257 + row) * 8 + (ac4 & 1) * 4;
            *(uint2*)&aLds[0][off] = q0;
            *(uint2*)&aLds[1][off] = q1;
            *(uint2*)&aLds[2][off] = q2;
        }
        __syncthreads();

        s16x8 B0[4], B1[4], B2[4];
        #pragma unroll
        for (int nt = 0; nt < 4; ++nt) {
            const int boff = (lq * 65 + nt * 16 + lr) * 8;
            B0[nt] = *(const s16x8*)&bLds[0][boff];
            B1[nt] = *(const s16x8*)&bLds[1][boff];
            B2[nt] = *(const s16x8*)&bLds[2][boff];
        }
        #pragma unroll
        for (int mt = 0; mt < 4; ++mt) {
            const int aoff = (lq * 257 + waveM + mt * 16 + lr) * 8;
            s16x8 A0 = *(const s16x8*)&aLds[0][aoff];
            s16x8 A1 = *(const s16x8*)&aLds[1][aoff];
            s16x8 A2 = *(const s16x8*)&aLds[2][aoff];
            #pragma unroll
            for (int nt = 0; nt < 4; ++nt) {
                f32x4 c = acc[mt][nt];
                c = mfma16(A0, B0[nt], c);
                c = mfma16(A0, B1[nt], c);
                c = mfma16(A1, B0[nt], c);
                c = mfma16(A1, B1[nt], c);
                c = mfma16(A0, B2[nt], c);
                c = mfma16(A2, B0[nt], c);
                acc[mt][nt] = c;
            }
        }
    }

    float bv[4];
    #pragma unroll
    for (int nt = 0; nt < 4; ++nt) bv[nt] = bias[n0 + nt * 16 + lr];

    if (!FUSE) {
        #pragma unroll
        for (int mt = 0; mt < 4; ++mt)
            #pragma unroll
            for (int nt = 0; nt < 4; ++nt)
                #pragma unroll
                for (int r = 0; r < 4; ++r) {
                    const int row = m0 + waveM + mt * 16 + lq * 4 + r;
                    out[(size_t)row * 1024 + n0 + nt * 16 + lr] =
                        fmaxf(acc[mt][nt][r] + bv[nt], 0.f);
                }
    } else {
        float wv[4];
        #pragma unroll
        for (int nt = 0; nt < 4; ++nt) wv[nt] = W3[n0 + nt * 16 + lr];
        #pragma unroll
        for (int mt = 0; mt < 4; ++mt)
            #pragma unroll
            for (int r = 0; r < 4; ++r) {
                float v = 0.f;
                #pragma unroll
                for (int nt = 0; nt < 4; ++nt)
                    v += fmaxf(acc[mt][nt][r] + bv[nt], 0.f) * wv[nt];
                v += __shfl_xor(v, 1);
                v += __shfl_xor(v, 2);
                v += __shfl_xor(v, 4);
                v += __shfl_xor(v, 8);
                if (lr == 0)
                    out[(size_t)blockIdx.x * M_ + m0 + waveM + mt * 16 + lq * 4 + r] = v;
            }
    }
}

// ===========================================================================
// Top-K / gather / masks (shared by both paths)
// ===========================================================================
__device__ __forceinline__ uint64_t score_key(float s, int idx) {
    unsigned u = __float_as_uint(s);
    u = (u & 0x80000000u) ? ~u : (u | 0x80000000u);
    return ((uint64_t)u << 32) | (uint64_t)(0xFFFFFFFFu - (unsigned)idx);
}

__device__ __forceinline__ float compute_score(
    const float* __restrict__ partial, const float* __restrict__ mask,
    float b3v, int b, int i)
{
    const int m = b * TL_ + i;
    float s = b3v;
    #pragma unroll
    for (int cb = 0; cb < NPART; ++cb) s += partial[(size_t)cb * M_ + m];
    s -= (1.0f - mask[m]) * 10000.0f;
    return s;
}

__global__ __launch_bounds__(1024) void topk_kernel(
    const float* __restrict__ partial, const float* __restrict__ span_mask,
    const int* __restrict__ span_begin, const int* __restrict__ span_end,
    const int* __restrict__ seq_len, const float* __restrict__ b3,
    float* __restrict__ out, int* __restrict__ topk_ws)
{
    __shared__ uint64_t keys[NSORT];
    const int tid = threadIdx.x;
    const int b   = blockIdx.x;
    const float b3v = b3[0];

    for (int i = tid; i < NSORT; i += 1024) {
        if (i < TL_) {
            float s = compute_score(partial, span_mask, b3v, b, i);
            out[OFF_PRUNE + b * TL_ + i] = s;
            keys[i] = score_key(s, i);
        } else {
            keys[i] = 0ull;
        }
    }
    __syncthreads();

    for (unsigned kk = 2; kk <= NSORT; kk <<= 1) {
        for (unsigned j = kk >> 1; j > 0; j >>= 1) {
            for (unsigned i = (unsigned)tid; i < NSORT; i += 1024) {
                unsigned ixj = i ^ j;
                if (ixj > i) {
                    uint64_t x = keys[i], y = keys[ixj];
                    bool desc = ((i & kk) == 0);
                    if (desc ? (x < y) : (x > y)) { keys[i] = y; keys[ixj] = x; }
                }
            }
            __syncthreads();
        }
    }

    const uint64_t cutoff = keys[K_SPANS - 1];
    __syncthreads();

    unsigned* sScan = (unsigned*)keys;
    unsigned base = 0;
    const unsigned lane = tid & 63;
    const unsigned wv   = tid >> 6;
    for (int c = 0; c < TL_; c += 1024) {
        const int i = c + tid;
        bool flag = false; float s = 0.f;
        if (i < TL_) {
            s = compute_score(partial, span_mask, b3v, b, i);
            flag = (score_key(s, i) >= cutoff);
        }
        uint64_t bal = __ballot(flag);
        unsigned pre = (unsigned)__popcll(bal & ((1ull << lane) - 1ull));
        if (lane == 0) sScan[wv] = (unsigned)__popcll(bal);
        __syncthreads();
        unsigned woff = 0, tot = 0;
        for (int w = 0; w < 16; ++w) {
            unsigned v = sScan[w];
            if (w < (int)wv) woff += v;
            tot += v;
        }
        if (flag) {
            const int g = b * K_SPANS + (int)(base + woff + pre);
            topk_ws[g]        = i;
            out[OFF_TOP + g]  = (float)i;
            out[OFF_FSC + g]  = s;
            out[OFF_FBEG + g] = (float)span_begin[b * TL_ + i];
            out[OFF_FEND + g] = (float)span_end[b * TL_ + i];
        }
        base += tot;
        __syncthreads();
    }

    if (tid == 0)
        out[OFF_SL + b] = ceilf(0.4f * (float)seq_len[b]);
}

__global__ void gather_vecs(const float* __restrict__ span_vecs,
                            const int* __restrict__ topk_ws,
                            float* __restrict__ out)
{
    const int bk  = blockIdx.x;
    const int b   = bk / K_SPANS;
    const int row = topk_ws[bk];
    const float4* src = (const float4*)(span_vecs + ((size_t)b * TL_ + row) * D_);
    float4* dst = (float4*)(out + OFF_FVECS + (size_t)bk * D_);
    for (int j = threadIdx.x; j < D_ / 4; j += blockDim.x) dst[j] = src[j];
}

__global__ void masks_kernel(const int* __restrict__ seq_len,
                             float* __restrict__ out)
{
    const int idx = blockIdx.x * blockDim.x + threadIdx.x;
    if (idx >= B_ * K_SPANS * K_SPANS) return;
    const int b = idx / (K_SPANS * K_SPANS);
    const int r = idx - b * K_SPANS * K_SPANS;
    const int i = r / K_SPANS;
    const int j = r - i * K_SPANS;
    const int sl = (int)ceilf(0.4f * (float)seq_len[b]);
    const float v = (i < sl && j < sl) ? 1.0f : 0.0f;
    out[OFF_SQ + idx]  = v;
    out[OFF_TRI + idx] = (j <= i) ? v : 0.0f;
}

// ===========================================================================
extern "C" void kernel_launch(void* const* d_in, const int* in_sizes, int n_in,
                              void* d_out, int out_size, void* d_ws, size_t ws_size,
                              hipStream_t stream)
{
    const float* span_vecs  = (const float*)d_in[0];
    const float* span_mask  = (const float*)d_in[1];
    const int*   span_begin = (const int*)  d_in[2];
    const int*   span_end   = (const int*)  d_in[3];
    const int*   seq_len    = (const int*)  d_in[4];
    const float* W1 = (const float*)d_in[5];
    const float* b1 = (const float*)d_in[6];
    const float* W2 = (const float*)d_in[7];
    const float* b2 = (const float*)d_in[8];
    const float* W3 = (const float*)d_in[9];
    const float* b3 = (const float*)d_in[10];
    float* out = (float*)d_out;

    const size_t A1CH = (size_t)M_ * D_;        // ushorts per A1 panel chunk
    const size_t H1CH = (size_t)M_ * H_;        // ushorts per h1 panel chunk
    const size_t W1CH = (size_t)D_ * H_;        // ushorts per W1 panel chunk
    const size_t W2CH = (size_t)H_ * H_;        // ushorts per W2 panel chunk
    const size_t FAST_NEED =
        3 * A1CH * 2 + (size_t)M_ * H_ * 4 + 3 * H1CH * 2 +
        3 * W1CH * 2 + 3 * W2CH * 2 + (size_t)NPART * M_ * 4 + 4096;

    float* partial;
    int*   topk_ws;

    if (ws_size >= FAST_NEED) {
        // ---------------- fast path: LDS-free fragment-panel GEMMs ----------
        char* p = (char*)d_ws;
        ushort* a1p0 = (ushort*)p;  p += A1CH * 2;
        ushort* a1p1 = (ushort*)p;  p += A1CH * 2;
        ushort* a1p2 = (ushort*)p;  p += A1CH * 2;
        float*  h1   = (float*)p;   p += (size_t)M_ * H_ * 4;
        ushort* h1p0 = (ushort*)p;  p += H1CH * 2;
        ushort* h1p1 = (ushort*)p;  p += H1CH * 2;
        ushort* h1p2 = (ushort*)p;  p += H1CH * 2;
        ushort* w1p0 = (ushort*)p;  p += W1CH * 2;
        ushort* w1p1 = (ushort*)p;  p += W1CH * 2;
        ushort* w1p2 = (ushort*)p;  p += W1CH * 2;
        ushort* w2p0 = (ushort*)p;  p += W2CH * 2;
        ushort* w2p1 = (ushort*)p;  p += W2CH * 2;
        ushort* w2p2 = (ushort*)p;  p += W2CH * 2;
        partial      = (float*)p;   p += (size_t)NPART * M_ * 4;
        topk_ws      = (int*)p;

        split_a_panel<64><<<(M_ / 16) * 64 / 4, 256, 0, stream>>>(
            span_vecs, a1p0, a1p1, a1p2);
        split_w_frag<64><<<(H_ / 16) * 64 * 64 / 256, 256, 0, stream>>>(
            W1, w1p0, w1p1, w1p2);
        split_w_frag<32><<<(H_ / 16) * 32 * 64 / 256, 256, 0, stream>>>(
            W2, w2p0, w2p1, w2p2);

        gemm_frag<64, false><<<dim3(16, M_ / 256), 256, 0, stream>>>(
            a1p0, a1p1, a1p2, w1p0, w1p1, w1p2, b1, nullptr, h1);
        split_a_panel<32><<<(M_ / 16) * 32 / 4, 256, 0, stream>>>(
            h1, h1p0, h1p1, h1p2);
        gemm_frag<32, true><<<dim3(16, M_ / 256), 256, 0, stream>>>(
            h1p0, h1p1, h1p2, w2p0, w2p1, w2p2, b2, W3, partial);
    } else {
        // ---------------- fallback: R2 path (proven, ~147 MB) ---------------
        float*  h1   = (float*)d_ws;
        partial      = h1 + (size_t)M_ * H_;
        ushort* w1p0 = (ushort*)(partial + (size_t)NPART * M_);
        ushort* w1p1 = w1p0 + (size_t)256 * 1024 * 8;
        ushort* w1p2 = w1p1 + (size_t)256 * 1024 * 8;
        ushort* w2p0 = w1p2 + (size_t)256 * 1024 * 8;
        ushort* w2p1 = w2p0 + (size_t)128 * 1024 * 8;
        ushort* w2p2 = w2p1 + (size_t)128 * 1024 * 8;
        topk_ws      = (int*)(w2p2 + (size_t)128 * 1024 * 8);

        split_w_panel<<<(256 * 1024) / 256, 256, 0, stream>>>(W1, w1p0, w1p1, w1p2, 256);
        split_w_panel<<<(128 * 1024) / 256, 256, 0, stream>>>(W2, w2p0, w2p1, w2p2, 128);
        gemm_split<2048, false><<<dim3(16, 120), 256, 0, stream>>>(
            span_vecs, w1p0, w1p1, w1p2, b1, nullptr, h1);
        gemm_split<1024, true><<<dim3(16, 120), 256, 0, stream>>>(
            h1, w2p0, w2p1, w2p2, b2, W3, partial);
    }

    topk_kernel<<<B_, 1024, 0, stream>>>(
        partial, span_mask, span_begin, span_end, seq_len, b3, out, topk_ws);
    gather_vecs<<<B_ * K_SPANS, 256, 0, stream>>>(span_vecs, topk_ws, out);
    masks_kernel<<<(B_ * K_SPANS * K_SPANS + 255) / 256, 256, 0, stream>>>(
        seq_len, out);
}